// Round 11
// baseline (598.213 us; speedup 1.0000x reference)
//
#include <hip/hip_runtime.h>
#include <math.h>

#define BATCH 8
#define NPT   2048
#define DIM   32
#define RPB   32                      // rows per block: 2 strips of 16
#define STRIPS (RPB / 16)
#define CPW   (NPT / 4)               // 512 cols per wave
#define NT    (CPW / 16)              // 32 col-tiles of 16 per wave
#define L2E   1.44269504088896f
#define BN    (BATCH * NPT)

typedef __attribute__((ext_vector_type(8))) _Float16 half8;
typedef __attribute__((ext_vector_type(4))) float floatx4;
typedef unsigned short u16;
typedef unsigned int u32;

__device__ __forceinline__ u16 f2h_bits(float v) {
    _Float16 h = (_Float16)v;
    return *(u16*)&h;
}
__device__ __forceinline__ float exp2v(float x) { return __builtin_amdgcn_exp2f(x); }

struct CtSet {
    const u16* Ah;        // row-side plain fp16 [BATCH][NPT][DIM]
    const u16* Bh;        // col-side log2e-scaled fp16
    const float* tls;     // log2e*(pot+cw) on cols [BATCH][NPT]
    const float* qX;      // 0.5*||row||^2
    const float* bmIn;    // [BATCH][128] per-16 max of (pot+cw) on cols
    const float* cwNext;  // cw paired with out when out is later used as cols
    const float* prev;    // previous row potential (averaging)
    float* out;           // [BATCH][NPT]
    float* tlsOut;        // log2e*(out+cwNext)
    float* bmOut;         // [BATCH][128] per-16 max of (out+cwNext)
};
struct CtArgs { CtSet s[4]; int average; };

// out[l] = qX[l] - lse_k( x_l . y_k + pot[k] + cw[k] ), opt 0.5*(prev + .)
// Column bias folded into MFMA C-operand (R2/R8-proven rounding):
//   acc = L2E*x.y + (t_col - L2E*Tmax);  T = sum_k 2^acc;  lse = Tmax + ln T.
// XCD PINNING (R10, -19us): batch = bid & 7 -> per-XCD hot set ~0.6 MB,
// B-stream L2-resident.
// THIS ROUND: prefetch depth 2 -> 4 (clamped rotation, R5-proven pattern).
// 2-deep issued the B load only ~1 tile (~100 cyc) ahead of use; L2-hit
// latency ~200 cyc -> ~50-100 cyc exposed per tile (~35% of tile time).
// 4-deep gives ~3 tiles (~300 cyc) of distance. VGPR est ~60 < 64 cap.
__global__ __launch_bounds__(256, 8) void ct_kernel(CtArgs args) {
    const int bid  = blockIdx.x;
    const int batch = bid & 7;            // batch == XCD (dispatch round-robin)
    const int rest  = bid >> 3;           // 0..255 within the XCD
    const int slice = rest & 3;
    const int xb    = rest >> 2;          // 0..63 row-block
    const CtSet cs = args.s[slice];
    const int row0 = xb * RPB;
    const int tid  = threadIdx.x;
    const int w = tid >> 6, lane = tid & 63, n = lane & 15, quad = lane >> 4;
    const int qk = quad * 8;
    const size_t pbase = (size_t)batch * NPT * DIM;
    const size_t vbase = (size_t)batch * NPT;

    __shared__ float lsum[RPB][4];

    const u16* __restrict__ Ah = cs.Ah + pbase;
    const u16* __restrict__ Bh = cs.Bh + pbase;
    const float* __restrict__ tls = cs.tls + vbase;

    // A fragments for 2 row-strips: A[m=n][k=quad*8+j]
    half8 ah[STRIPS];
    #pragma unroll
    for (int s = 0; s < STRIPS; s++) {
        size_t off = (size_t)(row0 + s * 16 + n) * DIM + qk;
        ah[s] = *(const half8*)(Ah + off);
    }

    // Tmax = max_k (pot_k + cw_k): wave-local reduction of 128 16-row maxes
    float tmv = fmaxf(cs.bmIn[batch * 128 + lane], cs.bmIn[batch * 128 + 64 + lane]);
    #pragma unroll
    for (int m = 1; m < 64; m <<= 1) tmv = fmaxf(tmv, __shfl_xor(tmv, m, 64));
    const float Tmax = tmv;
    const float l2eTmax = L2E * Tmax;

    float sum[STRIPS][4];
    #pragma unroll
    for (int s = 0; s < STRIPS; s++)
        #pragma unroll
        for (int r = 0; r < 4; r++) sum[s][r] = 0.0f;

    // wave w owns cols [w*512, w*512+512): 32 tiles of 16, 4-deep reg
    // prefetch, NO barriers in the main loop -- waves fully decoupled.
    const int c0 = w * CPW + n;                    // this lane's col in tile 0
    const u16* bp = Bh + (size_t)c0 * DIM + qk;    // advances 16*DIM per tile
    const float* tp = tls + c0;

    half8 bb[4];
    float tt[4];
    bb[0] = *(const half8*)bp;                       tt[0] = tp[0];
    bb[1] = *(const half8*)(bp + (size_t)16 * DIM);  tt[1] = tp[16];

    auto tile = [&](half8 b, float t) {
        float bias = t - l2eTmax;                  // per-lane column bias
        floatx4 ci = (floatx4){bias, bias, bias, bias};
        floatx4 acc[STRIPS];
        #pragma unroll
        for (int s = 0; s < STRIPS; s++)
            acc[s] = __builtin_amdgcn_mfma_f32_16x16x32_f16(ah[s], b, ci, 0, 0, 0);
        #pragma unroll
        for (int s = 0; s < STRIPS; s++)
            #pragma unroll
            for (int r = 0; r < 4; r++)
                sum[s][r] += exp2v(acc[s][r]);
    };

    #pragma unroll 1
    for (int ch = 0; ch < NT; ch += 4) {
        #pragma unroll
        for (int j = 0; j < 4; j++) {
            int nx = ch + j + 2;
            int nxc = nx < NT ? nx : NT - 1;       // clamped, branch-free
            bb[(j + 2) & 3] = *(const half8*)(bp + (size_t)nxc * 16 * DIM);
            tt[(j + 2) & 3] = tp[nxc * 16];
            tile(bb[j], tt[j]);
        }
    }

    // reduce over the 16 n-lanes (this wave's cols), then across waves via LDS
    #pragma unroll
    for (int s = 0; s < STRIPS; s++)
        #pragma unroll
        for (int r = 0; r < 4; r++) {
            float v = sum[s][r];
            #pragma unroll
            for (int m = 1; m < 16; m <<= 1) v += __shfl_xor(v, m, 64);
            if (n == 0) lsum[s * 16 + quad * 4 + r][w] = v;
        }
    __syncthreads();

    if (tid < RPB) {
        float T = (lsum[tid][0] + lsum[tid][1]) + (lsum[tid][2] + lsum[tid][3]);
        int l = row0 + tid;
        float lse = Tmax + __logf(T);
        float val = cs.qX[vbase + l] - lse;
        if (args.average) val = 0.5f * (cs.prev[vbase + l] + val);
        cs.out[vbase + l] = val;
        float tc = val + cs.cwNext[vbase + l];
        cs.tlsOut[vbase + l] = L2E * tc;
        float bm = tc;
        #pragma unroll
        for (int m = 1; m < 16; m <<= 1) bm = fmaxf(bm, __shfl_xor(bm, m, 64));
        if ((tid & 15) == 0)
            cs.bmOut[batch * 128 + xb * STRIPS + (tid >> 4)] = bm;
    }
}

struct InitArgs {
    const float *x, *a, *y, *b;
    float *c_x, *c_y, *qx, *qy;
    u16 *xh, *yh, *xsh, *ysh;
    float *f0, *g0, *fx0, *fy0;
    float *tlsF0, *tlsG0, *tlsFx0, *tlsFy0;
    float *bmF0, *bmG0, *bmFx0, *bmFy0;
};

__global__ __launch_bounds__(256) void init_kernel(InitArgs ia) {
    int idx = blockIdx.x * 256 + threadIdx.x;
    if (idx >= BN) return;
    const float* xp = ia.x + (size_t)idx * DIM;
    const float* yp = ia.y + (size_t)idx * DIM;
    u32* xhp  = (u32*)ia.xh  + (size_t)idx * (DIM / 2);
    u32* yhp  = (u32*)ia.yh  + (size_t)idx * (DIM / 2);
    u32* xshp = (u32*)ia.xsh + (size_t)idx * (DIM / 2);
    u32* yshp = (u32*)ia.ysh + (size_t)idx * (DIM / 2);
    float sx = 0.f, sy = 0.f;
    #pragma unroll
    for (int d = 0; d < DIM; d += 2) {
        float v0 = xp[d], v1 = xp[d + 1];
        sx += v0 * v0 + v1 * v1;
        xhp[d / 2]  = (u32)f2h_bits(v0) | ((u32)f2h_bits(v1) << 16);
        xshp[d / 2] = (u32)f2h_bits(L2E * v0) | ((u32)f2h_bits(L2E * v1) << 16);
        float u0 = yp[d], u1 = yp[d + 1];
        sy += u0 * u0 + u1 * u1;
        yhp[d / 2]  = (u32)f2h_bits(u0) | ((u32)f2h_bits(u1) << 16);
        yshp[d / 2] = (u32)f2h_bits(L2E * u0) | ((u32)f2h_bits(L2E * u1) << 16);
    }
    float qxv = 0.5f * sx, qyv = 0.5f * sy;
    ia.qx[idx] = qxv; ia.qy[idx] = qyv;
    float cxv = __logf(ia.a[idx]) - qxv;
    float cyv = __logf(ia.b[idx]) - qyv;
    ia.c_x[idx] = cxv; ia.c_y[idx] = cyv;
    ia.f0[idx] = 0.f; ia.g0[idx] = 0.f; ia.fx0[idx] = 0.f; ia.fy0[idx] = 0.f;
    ia.tlsF0[idx] = L2E * cxv; ia.tlsG0[idx] = L2E * cyv;
    ia.tlsFx0[idx] = L2E * cxv; ia.tlsFy0[idx] = L2E * cyv;
    // per-16-row blockmax of (0 + cw)
    float mx = cxv, my = cyv;
    #pragma unroll
    for (int m = 1; m < 16; m <<= 1) {
        mx = fmaxf(mx, __shfl_xor(mx, m, 32));
        my = fmaxf(my, __shfl_xor(my, m, 32));
    }
    if ((threadIdx.x & 15) == 0) {
        int g = idx >> 4;   // == batch*128 + 16-row group
        ia.bmF0[g] = mx; ia.bmFx0[g] = mx;
        ia.bmG0[g] = my; ia.bmFy0[g] = my;
    }
}

__global__ __launch_bounds__(1024) void reduce_kernel(
        const float* __restrict__ a, const float* __restrict__ b,
        const float* __restrict__ ctA, const float* __restrict__ ctB,
        const float* __restrict__ ctX, const float* __restrict__ ctY,
        float* __restrict__ out) {
    float acc = 0.f;
    for (int idx = threadIdx.x; idx < BN; idx += 1024) {
        acc += a[idx] * (ctA[idx] - ctX[idx]) + b[idx] * (ctB[idx] - ctY[idx]);
    }
    #pragma unroll
    for (int off = 32; off > 0; off >>= 1) acc += __shfl_down(acc, off, 64);
    __shared__ float sm[16];
    if ((threadIdx.x & 63) == 0) sm[threadIdx.x >> 6] = acc;
    __syncthreads();
    if (threadIdx.x == 0) {
        float t = 0.f;
        #pragma unroll
        for (int i = 0; i < 16; i++) t += sm[i];
        out[0] = t / (float)BATCH;
    }
}

extern "C" void kernel_launch(void* const* d_in, const int* in_sizes, int n_in,
                              void* d_out, int out_size, void* d_ws, size_t ws_size,
                              hipStream_t stream) {
    const float* x = (const float*)d_in[0];
    const float* a = (const float*)d_in[1];
    const float* y = (const float*)d_in[2];
    const float* b = (const float*)d_in[3];
    float* out = (float*)d_out;

    float* ws = (float*)d_ws;
    float* c_x = ws + 0 * BN;
    float* c_y = ws + 1 * BN;
    float* qx  = ws + 2 * BN;
    float* qy  = ws + 3 * BN;
    float* fb[2]  = { ws + 4 * BN,  ws + 5 * BN };
    float* gb[2]  = { ws + 6 * BN,  ws + 7 * BN };
    float* fxb[2] = { ws + 8 * BN,  ws + 9 * BN };
    float* fyb[2] = { ws + 10 * BN, ws + 11 * BN };
    float* ctA = ws + 12 * BN;
    float* ctB = ws + 13 * BN;
    float* ctX = ws + 14 * BN;
    float* ctY = ws + 15 * BN;
    float* tlsF[2]  = { ws + 16 * BN, ws + 17 * BN };
    float* tlsG[2]  = { ws + 18 * BN, ws + 19 * BN };
    float* tlsFx[2] = { ws + 20 * BN, ws + 21 * BN };
    float* tlsFy[2] = { ws + 22 * BN, ws + 23 * BN };
    float* dummyT = ws + 24 * BN;
    float* small = ws + 25 * BN;
    float* bmF[2]  = { small + 0 * 1024, small + 1 * 1024 };
    float* bmG[2]  = { small + 2 * 1024, small + 3 * 1024 };
    float* bmFx[2] = { small + 4 * 1024, small + 5 * 1024 };
    float* bmFy[2] = { small + 6 * 1024, small + 7 * 1024 };
    float* dummyB = small + 8 * 1024;
    u16* bf = (u16*)(small + 10 * 1024);
    const size_t AS = (size_t)BN * DIM;
    u16* xh  = bf + 0 * AS;   // plain fp16 x
    u16* yh  = bf + 1 * AS;   // plain fp16 y
    u16* xsh = bf + 2 * AS;   // L2E-scaled fp16 x
    u16* ysh = bf + 3 * AS;   // L2E-scaled fp16 y

    InitArgs ia;
    ia.x = x; ia.a = a; ia.y = y; ia.b = b;
    ia.c_x = c_x; ia.c_y = c_y; ia.qx = qx; ia.qy = qy;
    ia.xh = xh; ia.yh = yh; ia.xsh = xsh; ia.ysh = ysh;
    ia.f0 = fb[0]; ia.g0 = gb[0]; ia.fx0 = fxb[0]; ia.fy0 = fyb[0];
    ia.tlsF0 = tlsF[0]; ia.tlsG0 = tlsG[0]; ia.tlsFx0 = tlsFx[0]; ia.tlsFy0 = tlsFy[0];
    ia.bmF0 = bmF[0]; ia.bmG0 = bmG[0]; ia.bmFx0 = bmFx[0]; ia.bmFy0 = bmFy[0];
    init_kernel<<<BN / 256, 256, 0, stream>>>(ia);

    const int nblk = (NPT / RPB) * 4 * BATCH;   // 2048, 1-D for XCD pinning
    int cur = 0;
    for (int it = 0; it < 10; it++) {
        CtArgs ar;
        ar.average = 1;
        // set0: fn = ct(g, log_b, kxy): rows X, cols Y
        ar.s[0] = { xh, ysh, tlsG[cur], qx, bmG[cur], c_x,
                    fb[cur], fb[1 - cur], tlsF[1 - cur], bmF[1 - cur] };
        // set1: gn = ct(f, log_a, kyx): rows Y, cols X
        ar.s[1] = { yh, xsh, tlsF[cur], qy, bmF[cur], c_y,
                    gb[cur], gb[1 - cur], tlsG[1 - cur], bmG[1 - cur] };
        // set2: sym x: rows X, cols X
        ar.s[2] = { xh, xsh, tlsFx[cur], qx, bmFx[cur], c_x,
                    fxb[cur], fxb[1 - cur], tlsFx[1 - cur], bmFx[1 - cur] };
        // set3: sym y: rows Y, cols Y
        ar.s[3] = { yh, ysh, tlsFy[cur], qy, bmFy[cur], c_y,
                    fyb[cur], fyb[1 - cur], tlsFy[1 - cur], bmFy[1 - cur] };
        ct_kernel<<<nblk, 256, 0, stream>>>(ar);
        cur ^= 1;
    }

    CtArgs fin;
    fin.average = 0;
    fin.s[0] = { xh, ysh, tlsG[cur], qx, bmG[cur], c_x, fb[cur], ctA, dummyT, dummyB };
    fin.s[1] = { yh, xsh, tlsF[cur], qy, bmF[cur], c_y, gb[cur], ctB, dummyT, dummyB };
    fin.s[2] = { xh, xsh, tlsFx[cur], qx, bmFx[cur], c_x, fxb[cur], ctX, dummyT, dummyB };
    fin.s[3] = { yh, ysh, tlsFy[cur], qy, bmFy[cur], c_y, fyb[cur], ctY, dummyT, dummyB };
    ct_kernel<<<nblk, 256, 0, stream>>>(fin);

    reduce_kernel<<<1, 1024, 0, stream>>>(a, b, ctA, ctB, ctX, ctY, out);
}

// Round 12
// 312.631 us; speedup vs baseline: 1.9135x; 1.9135x over previous
//
#include <hip/hip_runtime.h>
#include <math.h>

#define BATCH 8
#define NPT   2048
#define DIM   32
#define RPB   32                      // rows per block: 2 strips of 16
#define STRIPS (RPB / 16)
#define CPW   (NPT / 4)               // 512 cols per wave
#define NT    (CPW / 16)              // 32 col-tiles of 16 per wave
#define L2E   1.44269504088896f
#define BN    (BATCH * NPT)

typedef __attribute__((ext_vector_type(8))) _Float16 half8;
typedef __attribute__((ext_vector_type(4))) float floatx4;
typedef unsigned short u16;
typedef unsigned int u32;

__device__ __forceinline__ u16 f2h_bits(float v) {
    _Float16 h = (_Float16)v;
    return *(u16*)&h;
}
__device__ __forceinline__ float exp2v(float x) { return __builtin_amdgcn_exp2f(x); }

struct CtSet {
    const u16* Ah;        // row-side plain fp16 [BATCH][NPT][DIM]
    const u16* Bh;        // col-side log2e-scaled fp16
    const float* tls;     // log2e*(pot+cw) on cols [BATCH][NPT]
    const float* qX;      // 0.5*||row||^2
    const float* bmIn;    // [BATCH][128] per-16 max of (pot+cw) on cols
    const float* cwNext;  // cw paired with out when out is later used as cols
    const float* prev;    // previous row potential (averaging)
    float* out;           // [BATCH][NPT]
    float* tlsOut;        // log2e*(out+cwNext)
    float* bmOut;         // [BATCH][128] per-16 max of (out+cwNext)
};
struct CtArgs { CtSet s[4]; int average; };

// out[l] = qX[l] - lse_k( x_l . y_k + pot[k] + cw[k] ), opt 0.5*(prev + .)
// Column bias folded into MFMA C-operand (R2/R8-proven rounding):
//   acc = L2E*x.y + (t_col - L2E*Tmax);  T = sum_k 2^acc;  lse = Tmax + ln T.
// XCD PINNING (R10, -19us): batch = bid & 7 -> per-XCD hot set ~0.6 MB.
// 4-DEEP PREFETCH at launch_bounds(256,6): R11's (256,8) 64-VGPR cap made
// the allocator SPILL the bb[4]/tt[4] rotation (counters: WRITE_SIZE 43.5MB
// /dispatch of scratch traffic, VGPR=32) -> 2.7x regression. Cap 85 here
// fits the rotation (~65-70 VGPR); 6 waves/SIMD (wave count proven
// insensitive R0/R2/R3). Prefetch distance ~3 tiles (~300cy) > L2 ~200cy.
__global__ __launch_bounds__(256, 6) void ct_kernel(CtArgs args) {
    const int bid  = blockIdx.x;
    const int batch = bid & 7;            // batch == XCD (dispatch round-robin)
    const int rest  = bid >> 3;           // 0..255 within the XCD
    const int slice = rest & 3;
    const int xb    = rest >> 2;          // 0..63 row-block
    const CtSet cs = args.s[slice];
    const int row0 = xb * RPB;
    const int tid  = threadIdx.x;
    const int w = tid >> 6, lane = tid & 63, n = lane & 15, quad = lane >> 4;
    const int qk = quad * 8;
    const size_t pbase = (size_t)batch * NPT * DIM;
    const size_t vbase = (size_t)batch * NPT;

    __shared__ float lsum[RPB][4];

    const u16* __restrict__ Ah = cs.Ah + pbase;
    const u16* __restrict__ Bh = cs.Bh + pbase;
    const float* __restrict__ tls = cs.tls + vbase;

    // A fragments for 2 row-strips: A[m=n][k=quad*8+j]
    half8 ah[STRIPS];
    #pragma unroll
    for (int s = 0; s < STRIPS; s++) {
        size_t off = (size_t)(row0 + s * 16 + n) * DIM + qk;
        ah[s] = *(const half8*)(Ah + off);
    }

    // Tmax = max_k (pot_k + cw_k): wave-local reduction of 128 16-row maxes
    float tmv = fmaxf(cs.bmIn[batch * 128 + lane], cs.bmIn[batch * 128 + 64 + lane]);
    #pragma unroll
    for (int m = 1; m < 64; m <<= 1) tmv = fmaxf(tmv, __shfl_xor(tmv, m, 64));
    const float Tmax = tmv;
    const float l2eTmax = L2E * Tmax;

    float sum[STRIPS][4];
    #pragma unroll
    for (int s = 0; s < STRIPS; s++)
        #pragma unroll
        for (int r = 0; r < 4; r++) sum[s][r] = 0.0f;

    // wave w owns cols [w*512, w*512+512): 32 tiles of 16, 4-deep reg
    // prefetch, NO barriers in the main loop -- waves fully decoupled.
    const int c0 = w * CPW + n;                    // this lane's col in tile 0
    const u16* bp = Bh + (size_t)c0 * DIM + qk;    // advances 16*DIM per tile
    const float* tp = tls + c0;

    half8 bb[4];
    float tt[4];
    bb[0] = *(const half8*)bp;                       tt[0] = tp[0];
    bb[1] = *(const half8*)(bp + (size_t)16 * DIM);  tt[1] = tp[16];

    auto tile = [&](half8 b, float t) {
        float bias = t - l2eTmax;                  // per-lane column bias
        floatx4 ci = (floatx4){bias, bias, bias, bias};
        floatx4 acc[STRIPS];
        #pragma unroll
        for (int s = 0; s < STRIPS; s++)
            acc[s] = __builtin_amdgcn_mfma_f32_16x16x32_f16(ah[s], b, ci, 0, 0, 0);
        #pragma unroll
        for (int s = 0; s < STRIPS; s++)
            #pragma unroll
            for (int r = 0; r < 4; r++)
                sum[s][r] += exp2v(acc[s][r]);
    };

    #pragma unroll 1
    for (int ch = 0; ch < NT; ch += 4) {
        #pragma unroll
        for (int j = 0; j < 4; j++) {
            int nx = ch + j + 2;
            int nxc = nx < NT ? nx : NT - 1;       // clamped, branch-free
            bb[(j + 2) & 3] = *(const half8*)(bp + (size_t)nxc * 16 * DIM);
            tt[(j + 2) & 3] = tp[nxc * 16];
            tile(bb[j], tt[j]);
        }
    }

    // reduce over the 16 n-lanes (this wave's cols), then across waves via LDS
    #pragma unroll
    for (int s = 0; s < STRIPS; s++)
        #pragma unroll
        for (int r = 0; r < 4; r++) {
            float v = sum[s][r];
            #pragma unroll
            for (int m = 1; m < 16; m <<= 1) v += __shfl_xor(v, m, 64);
            if (n == 0) lsum[s * 16 + quad * 4 + r][w] = v;
        }
    __syncthreads();

    if (tid < RPB) {
        float T = (lsum[tid][0] + lsum[tid][1]) + (lsum[tid][2] + lsum[tid][3]);
        int l = row0 + tid;
        float lse = Tmax + __logf(T);
        float val = cs.qX[vbase + l] - lse;
        if (args.average) val = 0.5f * (cs.prev[vbase + l] + val);
        cs.out[vbase + l] = val;
        float tc = val + cs.cwNext[vbase + l];
        cs.tlsOut[vbase + l] = L2E * tc;
        float bm = tc;
        #pragma unroll
        for (int m = 1; m < 16; m <<= 1) bm = fmaxf(bm, __shfl_xor(bm, m, 64));
        if ((tid & 15) == 0)
            cs.bmOut[batch * 128 + xb * STRIPS + (tid >> 4)] = bm;
    }
}

struct InitArgs {
    const float *x, *a, *y, *b;
    float *c_x, *c_y, *qx, *qy;
    u16 *xh, *yh, *xsh, *ysh;
    float *f0, *g0, *fx0, *fy0;
    float *tlsF0, *tlsG0, *tlsFx0, *tlsFy0;
    float *bmF0, *bmG0, *bmFx0, *bmFy0;
};

__global__ __launch_bounds__(256) void init_kernel(InitArgs ia) {
    int idx = blockIdx.x * 256 + threadIdx.x;
    if (idx >= BN) return;
    const float* xp = ia.x + (size_t)idx * DIM;
    const float* yp = ia.y + (size_t)idx * DIM;
    u32* xhp  = (u32*)ia.xh  + (size_t)idx * (DIM / 2);
    u32* yhp  = (u32*)ia.yh  + (size_t)idx * (DIM / 2);
    u32* xshp = (u32*)ia.xsh + (size_t)idx * (DIM / 2);
    u32* yshp = (u32*)ia.ysh + (size_t)idx * (DIM / 2);
    float sx = 0.f, sy = 0.f;
    #pragma unroll
    for (int d = 0; d < DIM; d += 2) {
        float v0 = xp[d], v1 = xp[d + 1];
        sx += v0 * v0 + v1 * v1;
        xhp[d / 2]  = (u32)f2h_bits(v0) | ((u32)f2h_bits(v1) << 16);
        xshp[d / 2] = (u32)f2h_bits(L2E * v0) | ((u32)f2h_bits(L2E * v1) << 16);
        float u0 = yp[d], u1 = yp[d + 1];
        sy += u0 * u0 + u1 * u1;
        yhp[d / 2]  = (u32)f2h_bits(u0) | ((u32)f2h_bits(u1) << 16);
        yshp[d / 2] = (u32)f2h_bits(L2E * u0) | ((u32)f2h_bits(L2E * u1) << 16);
    }
    float qxv = 0.5f * sx, qyv = 0.5f * sy;
    ia.qx[idx] = qxv; ia.qy[idx] = qyv;
    float cxv = __logf(ia.a[idx]) - qxv;
    float cyv = __logf(ia.b[idx]) - qyv;
    ia.c_x[idx] = cxv; ia.c_y[idx] = cyv;
    ia.f0[idx] = 0.f; ia.g0[idx] = 0.f; ia.fx0[idx] = 0.f; ia.fy0[idx] = 0.f;
    ia.tlsF0[idx] = L2E * cxv; ia.tlsG0[idx] = L2E * cyv;
    ia.tlsFx0[idx] = L2E * cxv; ia.tlsFy0[idx] = L2E * cyv;
    // per-16-row blockmax of (0 + cw)
    float mx = cxv, my = cyv;
    #pragma unroll
    for (int m = 1; m < 16; m <<= 1) {
        mx = fmaxf(mx, __shfl_xor(mx, m, 32));
        my = fmaxf(my, __shfl_xor(my, m, 32));
    }
    if ((threadIdx.x & 15) == 0) {
        int g = idx >> 4;   // == batch*128 + 16-row group
        ia.bmF0[g] = mx; ia.bmFx0[g] = mx;
        ia.bmG0[g] = my; ia.bmFy0[g] = my;
    }
}

__global__ __launch_bounds__(1024) void reduce_kernel(
        const float* __restrict__ a, const float* __restrict__ b,
        const float* __restrict__ ctA, const float* __restrict__ ctB,
        const float* __restrict__ ctX, const float* __restrict__ ctY,
        float* __restrict__ out) {
    float acc = 0.f;
    for (int idx = threadIdx.x; idx < BN; idx += 1024) {
        acc += a[idx] * (ctA[idx] - ctX[idx]) + b[idx] * (ctB[idx] - ctY[idx]);
    }
    #pragma unroll
    for (int off = 32; off > 0; off >>= 1) acc += __shfl_down(acc, off, 64);
    __shared__ float sm[16];
    if ((threadIdx.x & 63) == 0) sm[threadIdx.x >> 6] = acc;
    __syncthreads();
    if (threadIdx.x == 0) {
        float t = 0.f;
        #pragma unroll
        for (int i = 0; i < 16; i++) t += sm[i];
        out[0] = t / (float)BATCH;
    }
}

extern "C" void kernel_launch(void* const* d_in, const int* in_sizes, int n_in,
                              void* d_out, int out_size, void* d_ws, size_t ws_size,
                              hipStream_t stream) {
    const float* x = (const float*)d_in[0];
    const float* a = (const float*)d_in[1];
    const float* y = (const float*)d_in[2];
    const float* b = (const float*)d_in[3];
    float* out = (float*)d_out;

    float* ws = (float*)d_ws;
    float* c_x = ws + 0 * BN;
    float* c_y = ws + 1 * BN;
    float* qx  = ws + 2 * BN;
    float* qy  = ws + 3 * BN;
    float* fb[2]  = { ws + 4 * BN,  ws + 5 * BN };
    float* gb[2]  = { ws + 6 * BN,  ws + 7 * BN };
    float* fxb[2] = { ws + 8 * BN,  ws + 9 * BN };
    float* fyb[2] = { ws + 10 * BN, ws + 11 * BN };
    float* ctA = ws + 12 * BN;
    float* ctB = ws + 13 * BN;
    float* ctX = ws + 14 * BN;
    float* ctY = ws + 15 * BN;
    float* tlsF[2]  = { ws + 16 * BN, ws + 17 * BN };
    float* tlsG[2]  = { ws + 18 * BN, ws + 19 * BN };
    float* tlsFx[2] = { ws + 20 * BN, ws + 21 * BN };
    float* tlsFy[2] = { ws + 22 * BN, ws + 23 * BN };
    float* dummyT = ws + 24 * BN;
    float* small = ws + 25 * BN;
    float* bmF[2]  = { small + 0 * 1024, small + 1 * 1024 };
    float* bmG[2]  = { small + 2 * 1024, small + 3 * 1024 };
    float* bmFx[2] = { small + 4 * 1024, small + 5 * 1024 };
    float* bmFy[2] = { small + 6 * 1024, small + 7 * 1024 };
    float* dummyB = small + 8 * 1024;
    u16* bf = (u16*)(small + 10 * 1024);
    const size_t AS = (size_t)BN * DIM;
    u16* xh  = bf + 0 * AS;   // plain fp16 x
    u16* yh  = bf + 1 * AS;   // plain fp16 y
    u16* xsh = bf + 2 * AS;   // L2E-scaled fp16 x
    u16* ysh = bf + 3 * AS;   // L2E-scaled fp16 y

    InitArgs ia;
    ia.x = x; ia.a = a; ia.y = y; ia.b = b;
    ia.c_x = c_x; ia.c_y = c_y; ia.qx = qx; ia.qy = qy;
    ia.xh = xh; ia.yh = yh; ia.xsh = xsh; ia.ysh = ysh;
    ia.f0 = fb[0]; ia.g0 = gb[0]; ia.fx0 = fxb[0]; ia.fy0 = fyb[0];
    ia.tlsF0 = tlsF[0]; ia.tlsG0 = tlsG[0]; ia.tlsFx0 = tlsFx[0]; ia.tlsFy0 = tlsFy[0];
    ia.bmF0 = bmF[0]; ia.bmG0 = bmG[0]; ia.bmFx0 = bmFx[0]; ia.bmFy0 = bmFy[0];
    init_kernel<<<BN / 256, 256, 0, stream>>>(ia);

    const int nblk = (NPT / RPB) * 4 * BATCH;   // 2048, 1-D for XCD pinning
    int cur = 0;
    for (int it = 0; it < 10; it++) {
        CtArgs ar;
        ar.average = 1;
        // set0: fn = ct(g, log_b, kxy): rows X, cols Y
        ar.s[0] = { xh, ysh, tlsG[cur], qx, bmG[cur], c_x,
                    fb[cur], fb[1 - cur], tlsF[1 - cur], bmF[1 - cur] };
        // set1: gn = ct(f, log_a, kyx): rows Y, cols X
        ar.s[1] = { yh, xsh, tlsF[cur], qy, bmF[cur], c_y,
                    gb[cur], gb[1 - cur], tlsG[1 - cur], bmG[1 - cur] };
        // set2: sym x: rows X, cols X
        ar.s[2] = { xh, xsh, tlsFx[cur], qx, bmFx[cur], c_x,
                    fxb[cur], fxb[1 - cur], tlsFx[1 - cur], bmFx[1 - cur] };
        // set3: sym y: rows Y, cols Y
        ar.s[3] = { yh, ysh, tlsFy[cur], qy, bmFy[cur], c_y,
                    fyb[cur], fyb[1 - cur], tlsFy[1 - cur], bmFy[1 - cur] };
        ct_kernel<<<nblk, 256, 0, stream>>>(ar);
        cur ^= 1;
    }

    CtArgs fin;
    fin.average = 0;
    fin.s[0] = { xh, ysh, tlsG[cur], qx, bmG[cur], c_x, fb[cur], ctA, dummyT, dummyB };
    fin.s[1] = { yh, xsh, tlsF[cur], qy, bmF[cur], c_y, gb[cur], ctB, dummyT, dummyB };
    fin.s[2] = { xh, xsh, tlsFx[cur], qx, bmFx[cur], c_x, fxb[cur], ctX, dummyT, dummyB };
    fin.s[3] = { yh, ysh, tlsFy[cur], qy, bmFy[cur], c_y, fyb[cur], ctY, dummyT, dummyB };
    ct_kernel<<<nblk, 256, 0, stream>>>(fin);

    reduce_kernel<<<1, 1024, 0, stream>>>(a, b, ctA, ctB, ctX, ctY, out);
}

// Round 13
// 282.369 us; speedup vs baseline: 2.1185x; 1.1072x over previous
//
#include <hip/hip_runtime.h>
#include <math.h>

#define BATCH 8
#define NPT   2048
#define DIM   32
#define RPB   64                      // rows per block: 4 strips of 16
#define STRIPS (RPB / 16)
#define NBLKR (NPT / RPB)             // 32 row blocks
#define CPW   (NPT / 4)               // 512 cols per wave
#define NT    (CPW / 16)              // 32 col-tiles of 16 per wave
#define L2E   1.44269504088896f
#define BN    (BATCH * NPT)

typedef __attribute__((ext_vector_type(8))) _Float16 half8;
typedef __attribute__((ext_vector_type(4))) float floatx4;
typedef unsigned short u16;
typedef unsigned int u32;

__device__ __forceinline__ u16 f2h_bits(float v) {
    _Float16 h = (_Float16)v;
    return *(u16*)&h;
}
__device__ __forceinline__ float exp2v(float x) { return __builtin_amdgcn_exp2f(x); }

struct CtSet {
    const u16* Ah;        // row-side plain fp16 [BATCH][NPT][DIM]
    const u16* Bh;        // col-side log2e-scaled fp16
    const float* tls;     // log2e*(pot+cw) on cols [BATCH][NPT]
    const float* qX;      // 0.5*||row||^2
    const float* bmIn;    // [BATCH][128] per-16 max of (pot+cw) on cols
    const float* cwNext;  // cw paired with out when out is later used as cols
    const float* prev;    // previous row potential (averaging)
    float* out;           // [BATCH][NPT]
    float* tlsOut;        // log2e*(out+cwNext)
    float* bmOut;         // [BATCH][128] per-16 max of (out+cwNext)
};
struct CtArgs { CtSet s[4]; int average; };

// out[l] = qX[l] - lse_k( x_l . y_k + pot[k] + cw[k] ), opt 0.5*(prev + .)
// Column bias in MFMA C-operand (R2/R8-proven rounding):
//   acc = L2E*x.y + (t_col - L2E*Tmax);  T = sum_k 2^acc;  lse = Tmax + ln T.
// XCD PINNING (R10, -19us): batch = bid & 7 -> per-XCD hot set one batch.
// RPB=64 (this round): L2-BW theory -- ct is per-XCD L2-read-bound
// (32 MB/XCD/launch at RPB=32; explains occupancy/ILP/issue insensitivity
// R8/R10/R12 + R3-vs-R2 delta). 64 rows/block halves B re-reads: 16 MB/XCD.
// Grid 1024 = 4 blocks/CU; launch_bounds(256,4) -> 128-VGPR cap (4-deep
// rotation at STRIPS=4 needs ~90; R11's spill was the 64 cap).
__global__ __launch_bounds__(256, 4) void ct_kernel(CtArgs args) {
    const int bid  = blockIdx.x;
    const int batch = bid & 7;            // batch == XCD (dispatch round-robin)
    const int rest  = bid >> 3;           // 0..127 within the XCD
    const int slice = rest & 3;
    const int xb    = rest >> 2;          // 0..31 row-block
    const CtSet cs = args.s[slice];
    const int row0 = xb * RPB;
    const int tid  = threadIdx.x;
    const int w = tid >> 6, lane = tid & 63, n = lane & 15, quad = lane >> 4;
    const int qk = quad * 8;
    const size_t pbase = (size_t)batch * NPT * DIM;
    const size_t vbase = (size_t)batch * NPT;

    __shared__ float lsum[RPB][4];

    const u16* __restrict__ Ah = cs.Ah + pbase;
    const u16* __restrict__ Bh = cs.Bh + pbase;
    const float* __restrict__ tls = cs.tls + vbase;

    // A fragments for 4 row-strips: A[m=n][k=quad*8+j]
    half8 ah[STRIPS];
    #pragma unroll
    for (int s = 0; s < STRIPS; s++) {
        size_t off = (size_t)(row0 + s * 16 + n) * DIM + qk;
        ah[s] = *(const half8*)(Ah + off);
    }

    // Tmax = max_k (pot_k + cw_k): wave-local reduction of 128 16-row maxes
    float tmv = fmaxf(cs.bmIn[batch * 128 + lane], cs.bmIn[batch * 128 + 64 + lane]);
    #pragma unroll
    for (int m = 1; m < 64; m <<= 1) tmv = fmaxf(tmv, __shfl_xor(tmv, m, 64));
    const float Tmax = tmv;
    const float l2eTmax = L2E * Tmax;

    float sum[STRIPS][4];
    #pragma unroll
    for (int s = 0; s < STRIPS; s++)
        #pragma unroll
        for (int r = 0; r < 4; r++) sum[s][r] = 0.0f;

    // wave w owns cols [w*512, w*512+512): 32 tiles of 16, 4-deep reg
    // prefetch, NO barriers in the main loop -- waves fully decoupled.
    const int c0 = w * CPW + n;                    // this lane's col in tile 0
    const u16* bp = Bh + (size_t)c0 * DIM + qk;    // advances 16*DIM per tile
    const float* tp = tls + c0;

    half8 bb[4];
    float tt[4];
    bb[0] = *(const half8*)bp;                       tt[0] = tp[0];
    bb[1] = *(const half8*)(bp + (size_t)16 * DIM);  tt[1] = tp[16];

    auto tile = [&](half8 b, float t) {
        float bias = t - l2eTmax;                  // per-lane column bias
        floatx4 ci = (floatx4){bias, bias, bias, bias};
        floatx4 acc[STRIPS];
        #pragma unroll
        for (int s = 0; s < STRIPS; s++)
            acc[s] = __builtin_amdgcn_mfma_f32_16x16x32_f16(ah[s], b, ci, 0, 0, 0);
        #pragma unroll
        for (int s = 0; s < STRIPS; s++)
            #pragma unroll
            for (int r = 0; r < 4; r++)
                sum[s][r] += exp2v(acc[s][r]);
    };

    #pragma unroll 1
    for (int ch = 0; ch < NT; ch += 4) {
        #pragma unroll
        for (int j = 0; j < 4; j++) {
            int nx = ch + j + 2;
            int nxc = nx < NT ? nx : NT - 1;       // clamped, branch-free
            bb[(j + 2) & 3] = *(const half8*)(bp + (size_t)nxc * 16 * DIM);
            tt[(j + 2) & 3] = tp[nxc * 16];
            tile(bb[j], tt[j]);
        }
    }

    // reduce over the 16 n-lanes (this wave's cols), then across waves via LDS
    #pragma unroll
    for (int s = 0; s < STRIPS; s++)
        #pragma unroll
        for (int r = 0; r < 4; r++) {
            float v = sum[s][r];
            #pragma unroll
            for (int m = 1; m < 16; m <<= 1) v += __shfl_xor(v, m, 64);
            if (n == 0) lsum[s * 16 + quad * 4 + r][w] = v;
        }
    __syncthreads();

    if (tid < RPB) {
        float T = (lsum[tid][0] + lsum[tid][1]) + (lsum[tid][2] + lsum[tid][3]);
        int l = row0 + tid;
        float lse = Tmax + __logf(T);
        float val = cs.qX[vbase + l] - lse;
        if (args.average) val = 0.5f * (cs.prev[vbase + l] + val);
        cs.out[vbase + l] = val;
        float tc = val + cs.cwNext[vbase + l];
        cs.tlsOut[vbase + l] = L2E * tc;
        float bm = tc;
        #pragma unroll
        for (int m = 1; m < 16; m <<= 1) bm = fmaxf(bm, __shfl_xor(bm, m, 64));
        if ((tid & 15) == 0)
            cs.bmOut[batch * 128 + xb * STRIPS + (tid >> 4)] = bm;
    }
}

struct InitArgs {
    const float *x, *a, *y, *b;
    float *c_x, *c_y, *qx, *qy;
    u16 *xh, *yh, *xsh, *ysh;
    float *f0, *g0, *fx0, *fy0;
    float *tlsF0, *tlsG0, *tlsFx0, *tlsFy0;
    float *bmF0, *bmG0, *bmFx0, *bmFy0;
};

__global__ __launch_bounds__(256) void init_kernel(InitArgs ia) {
    int idx = blockIdx.x * 256 + threadIdx.x;
    if (idx >= BN) return;
    const float* xp = ia.x + (size_t)idx * DIM;
    const float* yp = ia.y + (size_t)idx * DIM;
    u32* xhp  = (u32*)ia.xh  + (size_t)idx * (DIM / 2);
    u32* yhp  = (u32*)ia.yh  + (size_t)idx * (DIM / 2);
    u32* xshp = (u32*)ia.xsh + (size_t)idx * (DIM / 2);
    u32* yshp = (u32*)ia.ysh + (size_t)idx * (DIM / 2);
    float sx = 0.f, sy = 0.f;
    #pragma unroll
    for (int d = 0; d < DIM; d += 2) {
        float v0 = xp[d], v1 = xp[d + 1];
        sx += v0 * v0 + v1 * v1;
        xhp[d / 2]  = (u32)f2h_bits(v0) | ((u32)f2h_bits(v1) << 16);
        xshp[d / 2] = (u32)f2h_bits(L2E * v0) | ((u32)f2h_bits(L2E * v1) << 16);
        float u0 = yp[d], u1 = yp[d + 1];
        sy += u0 * u0 + u1 * u1;
        yhp[d / 2]  = (u32)f2h_bits(u0) | ((u32)f2h_bits(u1) << 16);
        yshp[d / 2] = (u32)f2h_bits(L2E * u0) | ((u32)f2h_bits(L2E * u1) << 16);
    }
    float qxv = 0.5f * sx, qyv = 0.5f * sy;
    ia.qx[idx] = qxv; ia.qy[idx] = qyv;
    float cxv = __logf(ia.a[idx]) - qxv;
    float cyv = __logf(ia.b[idx]) - qyv;
    ia.c_x[idx] = cxv; ia.c_y[idx] = cyv;
    ia.f0[idx] = 0.f; ia.g0[idx] = 0.f; ia.fx0[idx] = 0.f; ia.fy0[idx] = 0.f;
    ia.tlsF0[idx] = L2E * cxv; ia.tlsG0[idx] = L2E * cyv;
    ia.tlsFx0[idx] = L2E * cxv; ia.tlsFy0[idx] = L2E * cyv;
    // per-16-row blockmax of (0 + cw)
    float mx = cxv, my = cyv;
    #pragma unroll
    for (int m = 1; m < 16; m <<= 1) {
        mx = fmaxf(mx, __shfl_xor(mx, m, 32));
        my = fmaxf(my, __shfl_xor(my, m, 32));
    }
    if ((threadIdx.x & 15) == 0) {
        int g = idx >> 4;   // == batch*128 + 16-row group
        ia.bmF0[g] = mx; ia.bmFx0[g] = mx;
        ia.bmG0[g] = my; ia.bmFy0[g] = my;
    }
}

__global__ __launch_bounds__(1024) void reduce_kernel(
        const float* __restrict__ a, const float* __restrict__ b,
        const float* __restrict__ ctA, const float* __restrict__ ctB,
        const float* __restrict__ ctX, const float* __restrict__ ctY,
        float* __restrict__ out) {
    float acc = 0.f;
    for (int idx = threadIdx.x; idx < BN; idx += 1024) {
        acc += a[idx] * (ctA[idx] - ctX[idx]) + b[idx] * (ctB[idx] - ctY[idx]);
    }
    #pragma unroll
    for (int off = 32; off > 0; off >>= 1) acc += __shfl_down(acc, off, 64);
    __shared__ float sm[16];
    if ((threadIdx.x & 63) == 0) sm[threadIdx.x >> 6] = acc;
    __syncthreads();
    if (threadIdx.x == 0) {
        float t = 0.f;
        #pragma unroll
        for (int i = 0; i < 16; i++) t += sm[i];
        out[0] = t / (float)BATCH;
    }
}

extern "C" void kernel_launch(void* const* d_in, const int* in_sizes, int n_in,
                              void* d_out, int out_size, void* d_ws, size_t ws_size,
                              hipStream_t stream) {
    const float* x = (const float*)d_in[0];
    const float* a = (const float*)d_in[1];
    const float* y = (const float*)d_in[2];
    const float* b = (const float*)d_in[3];
    float* out = (float*)d_out;

    float* ws = (float*)d_ws;
    float* c_x = ws + 0 * BN;
    float* c_y = ws + 1 * BN;
    float* qx  = ws + 2 * BN;
    float* qy  = ws + 3 * BN;
    float* fb[2]  = { ws + 4 * BN,  ws + 5 * BN };
    float* gb[2]  = { ws + 6 * BN,  ws + 7 * BN };
    float* fxb[2] = { ws + 8 * BN,  ws + 9 * BN };
    float* fyb[2] = { ws + 10 * BN, ws + 11 * BN };
    float* ctA = ws + 12 * BN;
    float* ctB = ws + 13 * BN;
    float* ctX = ws + 14 * BN;
    float* ctY = ws + 15 * BN;
    float* tlsF[2]  = { ws + 16 * BN, ws + 17 * BN };
    float* tlsG[2]  = { ws + 18 * BN, ws + 19 * BN };
    float* tlsFx[2] = { ws + 20 * BN, ws + 21 * BN };
    float* tlsFy[2] = { ws + 22 * BN, ws + 23 * BN };
    float* dummyT = ws + 24 * BN;
    float* small = ws + 25 * BN;
    float* bmF[2]  = { small + 0 * 1024, small + 1 * 1024 };
    float* bmG[2]  = { small + 2 * 1024, small + 3 * 1024 };
    float* bmFx[2] = { small + 4 * 1024, small + 5 * 1024 };
    float* bmFy[2] = { small + 6 * 1024, small + 7 * 1024 };
    float* dummyB = small + 8 * 1024;
    u16* bf = (u16*)(small + 10 * 1024);
    const size_t AS = (size_t)BN * DIM;
    u16* xh  = bf + 0 * AS;   // plain fp16 x
    u16* yh  = bf + 1 * AS;   // plain fp16 y
    u16* xsh = bf + 2 * AS;   // L2E-scaled fp16 x
    u16* ysh = bf + 3 * AS;   // L2E-scaled fp16 y

    InitArgs ia;
    ia.x = x; ia.a = a; ia.y = y; ia.b = b;
    ia.c_x = c_x; ia.c_y = c_y; ia.qx = qx; ia.qy = qy;
    ia.xh = xh; ia.yh = yh; ia.xsh = xsh; ia.ysh = ysh;
    ia.f0 = fb[0]; ia.g0 = gb[0]; ia.fx0 = fxb[0]; ia.fy0 = fyb[0];
    ia.tlsF0 = tlsF[0]; ia.tlsG0 = tlsG[0]; ia.tlsFx0 = tlsFx[0]; ia.tlsFy0 = tlsFy[0];
    ia.bmF0 = bmF[0]; ia.bmG0 = bmG[0]; ia.bmFx0 = bmFx[0]; ia.bmFy0 = bmFy[0];
    init_kernel<<<BN / 256, 256, 0, stream>>>(ia);

    const int nblk = NBLKR * 4 * BATCH;   // 1024, 1-D for XCD pinning
    int cur = 0;
    for (int it = 0; it < 10; it++) {
        CtArgs ar;
        ar.average = 1;
        // set0: fn = ct(g, log_b, kxy): rows X, cols Y
        ar.s[0] = { xh, ysh, tlsG[cur], qx, bmG[cur], c_x,
                    fb[cur], fb[1 - cur], tlsF[1 - cur], bmF[1 - cur] };
        // set1: gn = ct(f, log_a, kyx): rows Y, cols X
        ar.s[1] = { yh, xsh, tlsF[cur], qy, bmF[cur], c_y,
                    gb[cur], gb[1 - cur], tlsG[1 - cur], bmG[1 - cur] };
        // set2: sym x: rows X, cols X
        ar.s[2] = { xh, xsh, tlsFx[cur], qx, bmFx[cur], c_x,
                    fxb[cur], fxb[1 - cur], tlsFx[1 - cur], bmFx[1 - cur] };
        // set3: sym y: rows Y, cols Y
        ar.s[3] = { yh, ysh, tlsFy[cur], qy, bmFy[cur], c_y,
                    fyb[cur], fyb[1 - cur], tlsFy[1 - cur], bmFy[1 - cur] };
        ct_kernel<<<nblk, 256, 0, stream>>>(ar);
        cur ^= 1;
    }

    CtArgs fin;
    fin.average = 0;
    fin.s[0] = { xh, ysh, tlsG[cur], qx, bmG[cur], c_x, fb[cur], ctA, dummyT, dummyB };
    fin.s[1] = { yh, xsh, tlsF[cur], qy, bmF[cur], c_y, gb[cur], ctB, dummyT, dummyB };
    fin.s[2] = { xh, xsh, tlsFx[cur], qx, bmFx[cur], c_x, fxb[cur], ctX, dummyT, dummyB };
    fin.s[3] = { yh, ysh, tlsFy[cur], qy, bmFy[cur], c_y, fyb[cur], ctY, dummyT, dummyB };
    ct_kernel<<<nblk, 256, 0, stream>>>(fin);

    reduce_kernel<<<1, 1024, 0, stream>>>(a, b, ctA, ctB, ctX, ctY, out);
}